// Round 10
// baseline (54.175 us; speedup 1.0000x reference)
//
#include <hip/hip_runtime.h>

// B=8, N=16384, E=64, F=64. Positions = B*N = 131072.
// Y[f, (p,i)] = sum_{k=0..191} Mcat[f][k] * T[p][k][i];  Mcat = [A|Bw|C].
// R10 = R9 + 5 blocks/CU: grid 1280 (=5*256), unit-strided schedule over
// 8192 position-units (blocks 0..511 run 7 units, 512..1279 run 6).
// R9 left 25% residency unclaimed (1024 blocks = 4/CU with 30.7KB LDS).

#define NPOS   131072
#define PB     16            // positions per unit
#define NC     (PB * 3)      // 48 N-columns per unit
#define NUNITS (NPOS / PB)   // 8192
#define GRID   1280          // 5 blocks/CU * 256 CU
#define THREADS 256          // 4 waves; wave w owns f-tile [16w,16w+16)
#define PPW    4             // positions per wave per unit

typedef _Float16 half8 __attribute__((ext_vector_type(8)));
typedef float floatx4 __attribute__((ext_vector_type(4)));

__global__ __launch_bounds__(THREADS, 4)
void fused_mfma(const float* __restrict__ X, const float* __restrict__ J,
                const float* __restrict__ A, const float* __restrict__ Bw,
                const float* __restrict__ Cm, float* __restrict__ Y) {
    // Terms: kappa = ks*32 + kg*8 + j, kg slot XOR-swizzled by ((n>>1)&3)
    // (R4-verified 0-conflict reads).
    __shared__ _Float16 Tl[6][NC][4][8];     // 18432 B
    // Y staging: 16B chunks XOR-permuted c' = c ^ ((c>>4)&15) (involution
    // within 256B; R7/R8-verified conflicts 3.9M -> ~0.8M).
    __shared__ float Ys[PB * 192];           // 12288 B   (total 30720 B)

    const int lane = threadIdx.x & 63;
    const int w    = threadIdx.x >> 6;
    const int tid  = threadIdx.x;
    const int bid  = blockIdx.x;

    // Units for this block: u(t) = bid + t*GRID, t = 0..NU-1 (NU = 6 or 7).
    const int NU = (NUNITS - bid + GRID - 1) / GRID;

    // ---- Mcat fragments in registers for the whole kernel (6 frags/wave).
    const int fa  = w * 16 + (lane & 15);
    const int kgA = lane >> 4;
    half8 afrag[6];
    #pragma unroll
    for (int ks = 0; ks < 6; ++ks) {
        const float* mat = (ks < 2) ? A : (ks < 4 ? Bw : Cm);
        const float* src = mat + fa * 64 + (ks & 1) * 32 + kgA * 8;
        float4 lo = *(const float4*)src;
        float4 hi = *(const float4*)(src + 4);
        half8 h;
        h[0] = (_Float16)lo.x; h[1] = (_Float16)lo.y;
        h[2] = (_Float16)lo.z; h[3] = (_Float16)lo.w;
        h[4] = (_Float16)hi.x; h[5] = (_Float16)hi.y;
        h[6] = (_Float16)hi.z; h[7] = (_Float16)hi.w;
        afrag[ks] = h;
    }

    // P1 write coords (e = lane): ks = 2t + (e>>5), kg = (e&31)>>3, j = e&7.
    const int ks0 = lane >> 5;
    const int kgW = (lane & 31) >> 3;
    const int jW  = lane & 7;
    // P2 B-frag read slot (swizzle-corrected; nt-independent: nt*16 % 4 == 0).
    const int kgR = (lane >> 4) ^ (((lane & 15) >> 1) & 3);

    // Two named prefetch buffers (static indexing only — R4/R8 spill lesson).
    float jrA[PPW][3], xrA[PPW][3], jrB[PPW][3], xrB[PPW][3];

#define LOAD_BODY(JR, XR, U)                                                  \
    {                                                                         \
        _Pragma("unroll")                                                     \
        for (int q = 0; q < PPW; ++q) {                                       \
            const int p = (U) * PB + w * PPW + q;                             \
            const float* jp = J + (size_t)(p * 64 + lane) * 3;                \
            const float* xp = X + (size_t)(p * 64 + lane) * 3;                \
            JR[q][0] = jp[0]; JR[q][1] = jp[1]; JR[q][2] = jp[2];             \
            XR[q][0] = xp[0]; XR[q][1] = xp[1]; XR[q][2] = xp[2];             \
        }                                                                     \
    }

#define P1_BODY(JR, XR)                                                       \
    {                                                                         \
        _Pragma("unroll")                                                     \
        for (int q = 0; q < PPW; ++q) {                                       \
            const int p_local = w * PPW + q;                                  \
            float ja = JR[q][0], jb = JR[q][1], jg = JR[q][2];                \
            float x0 = XR[q][0], x1 = XR[q][1], x2 = XR[q][2];                \
            float sa, ca, sb, cb, sg, cg;                                     \
            __sincosf(ja, &sa, &ca);                                          \
            __sincosf(jb, &sb, &cb);                                          \
            __sincosf(jg, &sg, &cg);                                          \
            float casb = ca * sb, sasb = sa * sb;                             \
            float r00 = ca * cb, r01 = casb * sg - sa * cg;                   \
            float r02 = casb * cg + sa * sg;                                  \
            float r10 = sa * cb, r11 = sasb * sg + ca * cg;                   \
            float r12 = sasb * cg - ca * sg;                                  \
            float r20 = -sb, r21 = cb * sg, r22 = cb * cg;                    \
            float v0 = fmaf(r00, x0, fmaf(r10, x1, r20 * x2));                \
            float v1 = fmaf(r01, x0, fmaf(r11, x1, r21 * x2));                \
            float v2 = fmaf(r02, x0, fmaf(r12, x1, r22 * x2));                \
            float ta[3], tb[3], tc[3];                                        \
            ta[0] = fmaf(r00, v0, r01 * v1);                                  \
            ta[1] = fmaf(r10, v0, r11 * v1);                                  \
            ta[2] = fmaf(r20, v0, r21 * v1);                                  \
            tb[0] = fmaf(r01, v0, -r00 * v1);                                 \
            tb[1] = fmaf(r11, v0, -r10 * v1);                                 \
            tb[2] = fmaf(r21, v0, -r20 * v1);                                 \
            tc[0] = r02 * v2; tc[1] = r12 * v2; tc[2] = r22 * v2;             \
            _Pragma("unroll")                                                 \
            for (int i = 0; i < 3; ++i) {                                     \
                const int n  = p_local * 3 + i;                               \
                const int kg = kgW ^ ((n >> 1) & 3);                          \
                Tl[0 + ks0][n][kg][jW] = (_Float16)ta[i];                     \
                Tl[2 + ks0][n][kg][jW] = (_Float16)tb[i];                     \
                Tl[4 + ks0][n][kg][jW] = (_Float16)tc[i];                     \
            }                                                                 \
        }                                                                     \
    }

#define P2_BODY()                                                             \
    {                                                                         \
        _Pragma("unroll")                                                     \
        for (int nt = 0; nt < 3; ++nt) {                                      \
            floatx4 acc = {0.f, 0.f, 0.f, 0.f};                               \
            _Pragma("unroll")                                                 \
            for (int ks = 0; ks < 6; ++ks) {                                  \
                half8 b = *(const half8*)&Tl[ks][nt * 16 + (lane & 15)][kgR][0]; \
                acc = __builtin_amdgcn_mfma_f32_16x16x32_f16(afrag[ks], b, acc, 0, 0, 0); \
            }                                                                 \
            const int n   = nt * 16 + (lane & 15);                            \
            const int pl2 = (n * 171) >> 9;   /* n/3 for n < 96 */            \
            const int i2  = n - pl2 * 3;                                      \
            const int fb  = w * 16 + (lane >> 4) * 4;                         \
            _Pragma("unroll")                                                 \
            for (int r = 0; r < 4; ++r) {                                     \
                const int z  = pl2 * 192 + (fb + r) * 3 + i2;                 \
                const int c  = z >> 2;                                        \
                const int zp = ((c ^ ((c >> 4) & 15)) << 2) | (z & 3);        \
                Ys[zp] = acc[r];                                              \
            }                                                                 \
        }                                                                     \
    }

#define STORE_BODY(U)                                                         \
    {                                                                         \
        float* yb = Y + (size_t)(U) * PB * 192;                               \
        _Pragma("unroll")                                                     \
        for (int k = 0; k < 3; ++k) {                                         \
            const int c  = tid + 256 * k;                                     \
            const int cp = c ^ ((c >> 4) & 15);                               \
            floatx4 v = *(const floatx4*)&Ys[cp * 4];                         \
            __builtin_nontemporal_store(v, (floatx4*)(yb + (size_t)c * 4));   \
        }                                                                     \
    }

    // ---- Pipeline: 2 barriers/unit, loads 2 units ahead. NU = 6 or 7.
    LOAD_BODY(jrA, xrA, bid);                      // t=0
    LOAD_BODY(jrB, xrB, bid + GRID);               // t=1 (always exists, NU>=6)
    P1_BODY(jrA, xrA);                             // Tl for t=0
    #pragma unroll 1
    for (int m = 0; m < 3; ++m) {
        const int t0 = 2 * m;
        // ---- t = t0 (even; prefetch into A for t0+2)
        __syncthreads();                           // Tl(t0) visible
        if (t0 + 2 < NU) LOAD_BODY(jrA, xrA, bid + (t0 + 2) * GRID);
        P2_BODY();
        __syncthreads();                           // Ys visible; Tl reads done
        STORE_BODY(bid + t0 * GRID);
        P1_BODY(jrB, xrB);                         // Tl for t0+1 (consumes B)
        // ---- t = t0+1 (odd; prefetch into B for t0+3)
        __syncthreads();
        if (t0 + 3 < NU) LOAD_BODY(jrB, xrB, bid + (t0 + 3) * GRID);
        P2_BODY();
        __syncthreads();
        STORE_BODY(bid + (t0 + 1) * GRID);
        if (t0 + 2 < NU) P1_BODY(jrA, xrA);        // Tl for t0+2 (consumes A)
    }
    // tail unit t=6 for blocks with NU==7
    if (NU == 7) {
        __syncthreads();
        P2_BODY();
        __syncthreads();
        STORE_BODY(bid + 6 * GRID);
    }
#undef LOAD_BODY
#undef P1_BODY
#undef P2_BODY
#undef STORE_BODY
}

extern "C" void kernel_launch(void* const* d_in, const int* in_sizes, int n_in,
                              void* d_out, int out_size, void* d_ws, size_t ws_size,
                              hipStream_t stream) {
    const float* X  = (const float*)d_in[0];
    const float* J  = (const float*)d_in[1];
    const float* A  = (const float*)d_in[2];
    const float* Bw = (const float*)d_in[3];
    const float* Cm = (const float*)d_in[4];
    float* Y = (float*)d_out;
    fused_mfma<<<GRID, THREADS, 0, stream>>>(X, J, A, Bw, Cm, Y);
}